// Round 7
// baseline (3857.307 us; speedup 1.0000x reference)
//
#include <hip/hip_runtime.h>
#include <hip/hip_bf16.h>

typedef _Float16 half4v __attribute__((ext_vector_type(4)));
typedef _Float16 half8v __attribute__((ext_vector_type(8)));
typedef float f32x4 __attribute__((ext_vector_type(4)));

#define T_STEPS 256
#define BATCH 64
#define NHID 512
#define NINP 512
#define MROWS (T_STEPS * BATCH)          // 16384
#define KDIM (2 * NINP)                  // 1024
#define NOUT (2 * NHID + NHID)           // 1536

#define NX 8           // XCDs
#define CPX 8          // chains per XCD
#define WPX 32         // WGs per XCD (1 per CU)
#define DPW 16         // hidden dims owned per WG

// ---------------------------------------------------------------- converts

__global__ __launch_bounds__(256) void k_convert_x(
    const float* __restrict__ inp, const float* __restrict__ sem,
    _Float16* __restrict__ xh) {
  int idx = blockIdx.x * 256 + threadIdx.x;
  const int G = MROWS * KDIM / 4;
  for (int g = idx; g < G; g += 2048 * 256) {
    int e = g * 4;
    int m = e >> 10, k = e & 1023;
    const float* src = (k < NINP) ? (inp + (size_t)m * NINP + k)
                                  : (sem + (size_t)m * NINP + (k - NINP));
    float4 v = *(const float4*)src;
    half4v o = { (_Float16)v.x, (_Float16)v.y, (_Float16)v.z, (_Float16)v.w };
    *(half4v*)(xh + (size_t)e) = o;
  }
}

// biasN folds BOTH the x-side and recurrent biases.
__global__ __launch_bounds__(256) void k_convert_w(
    const float* __restrict__ W_ioux, const float* __restrict__ W_fx,
    const float* __restrict__ b_ioux, const float* __restrict__ b_fx,
    const float* __restrict__ b_iouh, const float* __restrict__ b_Uh,
    _Float16* __restrict__ wbig, float* __restrict__ biasN) {
  int g = blockIdx.x * 256 + threadIdx.x;
  int e = g * 4;
  int n = e >> 10, k = e & 1023;
  const float* src = (n < 2 * NHID) ? (W_ioux + (size_t)n * KDIM + k)
                                    : (W_fx + (size_t)(n - 2 * NHID) * KDIM + k);
  float4 v = *(const float4*)src;
  half4v o = { (_Float16)v.x, (_Float16)v.y, (_Float16)v.z, (_Float16)v.w };
  *(half4v*)(wbig + (size_t)e) = o;
  if (g < NOUT)
    biasN[g] = (g < 2 * NHID) ? (b_ioux[g] + b_iouh[g])
                              : (b_fx[g - 2 * NHID] + b_Uh[g - 2 * NHID]);
}

__global__ __launch_bounds__(256) void k_convert_wrec(
    const float* __restrict__ W_iouh, const float* __restrict__ W_Uh,
    _Float16* __restrict__ wrec) {
  int g = blockIdx.x * 256 + threadIdx.x;
  int e = g * 4;
  const int NI = 2 * NHID * NHID;
  const float* src = (e < NI) ? (W_iouh + e) : (W_Uh + (e - NI));
  float4 v = *(const float4*)src;
  half4v o = { (_Float16)v.x, (_Float16)v.y, (_Float16)v.z, (_Float16)v.w };
  *(half4v*)(wrec + (size_t)e) = o;
}

// ---------------------------------------------------------------- GEMM

__device__ __forceinline__ void gload16(const void* g, void* l) {
  __builtin_amdgcn_global_load_lds(
      (const __attribute__((address_space(1))) unsigned int*)g,
      (__attribute__((address_space(3))) unsigned int*)l, 16, 0, 0);
}

__global__ __launch_bounds__(256) void gemm_bt(
    const _Float16* __restrict__ A, const _Float16* __restrict__ Bm,
    const float* __restrict__ biasN, float* __restrict__ C,
    int M, int N, int K) {
  __shared__ __align__(16) _Float16 As[128 * 32];
  __shared__ __align__(16) _Float16 Bs[128 * 32];
  const int tid = threadIdx.x;
  const int lane = tid & 63;
  const int w = tid >> 6;
  const int wr = w >> 1, wc = w & 1;
  const int nbm = M >> 7;
  const int bm = blockIdx.x % nbm, bn = blockIdx.x / nbm;
  const int m0 = bm << 7, n0 = bn << 7;
  const int lr = lane & 15, lh = lane >> 4;

  f32x4 acc[4][4] = {};

  for (int kk = 0; kk < K; kk += 32) {
#pragma unroll
    for (int c = 0; c < 2; ++c) {
      int L = (c * 256 + tid) * 16;
      int row = L >> 6, inrow = L & 63;
      gload16((const char*)A + ((size_t)(m0 + row) * K + kk) * 2 + inrow,
              (char*)As + L);
      gload16((const char*)Bm + ((size_t)(n0 + row) * K + kk) * 2 + inrow,
              (char*)Bs + L);
    }
    __syncthreads();
    half8v af[4], bf[4];
#pragma unroll
    for (int i = 0; i < 4; ++i)
      af[i] = *(const half8v*)&As[(wr * 64 + i * 16 + lr) * 32 + lh * 8];
#pragma unroll
    for (int i = 0; i < 4; ++i)
      bf[i] = *(const half8v*)&Bs[(wc * 64 + i * 16 + lr) * 32 + lh * 8];
#pragma unroll
    for (int i = 0; i < 4; ++i)
#pragma unroll
      for (int j = 0; j < 4; ++j)
        acc[i][j] = __builtin_amdgcn_mfma_f32_16x16x32_f16(af[i], bf[j], acc[i][j], 0, 0, 0);
    __syncthreads();
  }

#pragma unroll
  for (int i = 0; i < 4; ++i)
#pragma unroll
    for (int j = 0; j < 4; ++j) {
      int n = n0 + wc * 64 + j * 16 + lr;
      float bv = biasN[n];
#pragma unroll
      for (int q = 0; q < 4; ++q) {
        int m = m0 + wr * 64 + i * 16 + lh * 4 + q;
        C[(size_t)m * N + n] = acc[i][j][q] + bv;
      }
    }
}

// ---------------------------------------------------------------- recurrence
// 8 XCDs x 8 chains; 32 WGs/XCD (one per CU), WG owns 16 hidden dims.
// BOTH phases row-split (no partials): per step per WG stream = 32 z/r rows
// (32 KB) + 16 Uh rows (16 KB), amortized over 8 chains. Exchange = r*h and
// h vectors only (f16, 512 B write / 8 KB staged read per WG), all XCD-local
// via relaxed agent atomics (validated r2/3/4/6; cross-XCD is NOT coherent,
// r5). Only wave 0 polls flags; flags padded to 16 B.

__device__ __forceinline__ float dot8(half8v a, half8v b, float acc) {
  acc = __builtin_amdgcn_fdot2(__builtin_shufflevector(a, a, 0, 1),
                               __builtin_shufflevector(b, b, 0, 1), acc, false);
  acc = __builtin_amdgcn_fdot2(__builtin_shufflevector(a, a, 2, 3),
                               __builtin_shufflevector(b, b, 2, 3), acc, false);
  acc = __builtin_amdgcn_fdot2(__builtin_shufflevector(a, a, 4, 5),
                               __builtin_shufflevector(b, b, 4, 5), acc, false);
  acc = __builtin_amdgcn_fdot2(__builtin_shufflevector(a, a, 6, 7),
                               __builtin_shufflevector(b, b, 6, 7), acc, false);
  return acc;
}

__device__ __forceinline__ float sigm(float v) { return 1.f / (1.f + __expf(-v)); }

__device__ __forceinline__ void wait32(int* f, int need, int lane) {
  int v = need;
  if (lane < 32)
    v = __hip_atomic_load(&f[lane * 4], __ATOMIC_RELAXED, __HIP_MEMORY_SCOPE_AGENT);
  while (__any(v < need)) {
    __builtin_amdgcn_s_sleep(1);
    if (lane < 32)
      v = __hip_atomic_load(&f[lane * 4], __ATOMIC_RELAXED, __HIP_MEMORY_SCOPE_AGENT);
  }
}

__device__ __forceinline__ void st16a(unsigned short* p, _Float16 x) {
  __hip_atomic_store(p, __builtin_bit_cast(unsigned short, x),
                     __ATOMIC_RELAXED, __HIP_MEMORY_SCOPE_AGENT);
}

__global__ __launch_bounds__(256, 1) void recur7(
    const _Float16* __restrict__ Wrec, const float* __restrict__ hx,
    const float* __restrict__ proj, unsigned short* __restrict__ hbuf,
    unsigned short* __restrict__ rhbuf, int* __restrict__ flags,
    float* __restrict__ out) {
  __shared__ __align__(16) _Float16 hsh[CPX][NHID];    // full h_t (f16)
  __shared__ __align__(16) _Float16 rhsh[CPX][NHID];   // full r*h (f16)
  __shared__ float zsh[CPX][DPW];
  __shared__ float hfsh[CPX][DPW];                     // f32 h for own dims
  __shared__ float houts[CPX][DPW];

  const int bid = blockIdx.x;
  const int xcd = bid & 7;            // all comm partners share this XCD
  const int g = bid >> 3;             // 0..31: WG index within XCD
  const int tid = threadIdx.x;
  const int lane = tid & 63;
  const int w = tid >> 6;
  const int cb = xcd * CPX;           // chain base

  // phase-1 map: 32 rows x 8 K-eighths
  const int idx1 = tid >> 3, okt = tid & 7;
  const bool isz = idx1 < 16;
  const int dj = isz ? (g * DPW + idx1) : (512 + g * DPW + (idx1 - 16));
  // phase-2 map: 16 rows x 16 K-sixteenths
  const int idx2 = tid >> 4, kix = tid & 15;

  int* rhfl = flags + xcd * 256;             // stride-4 ints [0..127]
  int* hfl  = flags + xcd * 256 + 128;       // stride-4 ints [128..255]
  const _Float16* WU = Wrec + (size_t)1024 * 512;
  unsigned short* hbX = hbuf + (size_t)xcd * CPX * NHID;
  unsigned short* rbX = rhbuf + (size_t)xcd * CPX * NHID;

  // ---- init: f32 h for own dims; full h_0 staged to LDS
  if (tid < CPX * DPW) {
    int c = tid >> 4, d = tid & 15;
    hfsh[c][d] = hx[(size_t)(cb + c) * NHID + g * DPW + d];
  }
#pragma unroll
  for (int r = 0; r < 16; ++r) {
    int i2 = r * 256 + tid;                  // 0..4095
    int c = i2 >> 9, d = i2 & 511;
    hsh[c][d] = (_Float16)hx[(size_t)(cb + c) * NHID + d];
  }
  __syncthreads();

  for (int t = 0; t < T_STEPS; ++t) {
    const float* pt = proj + (size_t)(t * BATCH + cb) * NOUT;

    // ---- flag-independent proj loads (issue before any wait)
    float pzr[CPX], pf[CPX];
    if (okt == 0) {
#pragma unroll
      for (int c = 0; c < CPX; ++c) pzr[c] = pt[(size_t)c * NOUT + dj];
    }
    if (kix == 0) {
#pragma unroll
      for (int c = 0; c < CPX; ++c)
        pf[c] = pt[(size_t)c * NOUT + 1024 + g * DPW + idx2];
    }

    // ---- wait h_t (t>0), stage full h into LDS
    if (t > 0) {
      if (w == 0) wait32(hfl, t, lane);
      __syncthreads();
      asm volatile("" ::: "memory");
#pragma unroll
      for (int r = 0; r < 8; ++r) {
        int i2 = r * 256 + tid;              // 2048 dwords
        unsigned v = __hip_atomic_load((const unsigned*)hbX + i2,
                                       __ATOMIC_RELAXED, __HIP_MEMORY_SCOPE_AGENT);
        ((unsigned*)hsh)[i2] = v;
      }
      __syncthreads();
    }

    // ---- phase 1: z rows (idx1<16) / r rows (idx1>=16) for 8 chains
    float za[CPX] = {};
    const _Float16* wrow = Wrec + (size_t)dj * 512 + okt * 8;
#pragma unroll
    for (int j = 0; j < 8; ++j) {
      half8v wv = *(const half8v*)(wrow + j * 64);
#pragma unroll
      for (int c = 0; c < CPX; ++c) {
        half8v hv = *(const half8v*)&hsh[c][j * 64 + okt * 8];
        za[c] = dot8(wv, hv, za[c]);
      }
    }
#pragma unroll
    for (int c = 0; c < CPX; ++c) {
      za[c] += __shfl_xor(za[c], 1);
      za[c] += __shfl_xor(za[c], 2);
      za[c] += __shfl_xor(za[c], 4);
    }
    if (okt == 0) {
      if (isz) {
#pragma unroll
        for (int c = 0; c < CPX; ++c) zsh[c][idx1] = sigm(za[c] + pzr[c]);
      } else {
        int d = idx1 - 16;
#pragma unroll
        for (int c = 0; c < CPX; ++c) {
          float rv = sigm(za[c] + pzr[c]);
          st16a(&rbX[(size_t)c * NHID + g * DPW + d],
                (_Float16)(rv * hfsh[c][d]));
        }
      }
    }
    __syncthreads();                         // drain rh stores (vmcnt)
    if (tid == 0)
      __hip_atomic_store(&rhfl[g * 4], t + 1, __ATOMIC_RELAXED, __HIP_MEMORY_SCOPE_AGENT);

    // ---- wait full r*h, stage into LDS
    if (w == 0) wait32(rhfl, t + 1, lane);
    __syncthreads();
    asm volatile("" ::: "memory");
#pragma unroll
    for (int r = 0; r < 8; ++r) {
      int i2 = r * 256 + tid;
      unsigned v = __hip_atomic_load((const unsigned*)rbX + i2,
                                     __ATOMIC_RELAXED, __HIP_MEMORY_SCOPE_AGENT);
      ((unsigned*)rhsh)[i2] = v;
    }
    __syncthreads();

    // ---- phase 2: own 16 htilde rows, full K over r*h, 8 chains
    float ua[CPX] = {};
    const _Float16* wurow = WU + (size_t)(g * DPW + idx2) * 512 + kix * 8;
#pragma unroll
    for (int j = 0; j < 4; ++j) {
      half8v wv = *(const half8v*)(wurow + j * 128);
#pragma unroll
      for (int c = 0; c < CPX; ++c) {
        half8v rv2 = *(const half8v*)&rhsh[c][j * 128 + kix * 8];
        ua[c] = dot8(wv, rv2, ua[c]);
      }
    }
#pragma unroll
    for (int c = 0; c < CPX; ++c) {
      ua[c] += __shfl_xor(ua[c], 1);
      ua[c] += __shfl_xor(ua[c], 2);
      ua[c] += __shfl_xor(ua[c], 4);
      ua[c] += __shfl_xor(ua[c], 8);
    }
    if (kix == 0) {
#pragma unroll
      for (int c = 0; c < CPX; ++c) {
        float v = ua[c] + pf[c];
        float e = __expf(-2.f * fabsf(v));
        float th = (1.f - e) / (1.f + e);
        th = (v < 0.f) ? -th : th;
        float hold = hfsh[c][idx2];
        float hn = fmaf(zsh[c][idx2], th - hold, hold);
        hfsh[c][idx2] = hn;
        houts[c][idx2] = hn;
        st16a(&hbX[(size_t)c * NHID + g * DPW + idx2], (_Float16)hn);
      }
    }
    __syncthreads();                         // drain h stores (vmcnt) + lds
    if (tid == 0)
      __hip_atomic_store(&hfl[g * 4], t + 1, __ATOMIC_RELAXED, __HIP_MEMORY_SCOPE_AGENT);

    // out write (off critical path)
    if (tid < CPX * DPW) {
      int c = tid >> 4, d = tid & 15;
      out[(size_t)(t * BATCH + cb + c) * NHID + g * DPW + d] = houts[c][d];
    }
  }

  // ---- h_last
  if (tid < CPX * DPW) {
    int c = tid >> 4, d = tid & 15;
    out[(size_t)T_STEPS * BATCH * NHID + (size_t)(cb + c) * NHID + g * DPW + d] =
        hfsh[c][d];
  }
}

// ---------------------------------------------------------------- launcher

extern "C" void kernel_launch(void* const* d_in, const int* in_sizes, int n_in,
                              void* d_out, int out_size, void* d_ws, size_t ws_size,
                              hipStream_t stream) {
  const float* inputs = (const float*)d_in[0];
  const float* sememe = (const float*)d_in[1];
  const float* hx     = (const float*)d_in[2];
  const float* W_ioux = (const float*)d_in[3];
  const float* b_ioux = (const float*)d_in[4];
  const float* W_iouh = (const float*)d_in[5];
  const float* b_iouh = (const float*)d_in[6];
  const float* W_fx   = (const float*)d_in[7];
  const float* b_fx   = (const float*)d_in[8];
  const float* W_Uh   = (const float*)d_in[9];
  const float* b_Uh   = (const float*)d_in[10];
  float* out = (float*)d_out;

  char* ws = (char*)d_ws;
  _Float16* xh = (_Float16*)ws;   ws += (size_t)MROWS * KDIM * 2;
  _Float16* wbig = (_Float16*)ws; ws += (size_t)NOUT * KDIM * 2;
  float* biasN = (float*)ws;      ws += (size_t)NOUT * 4;
  _Float16* wrec = (_Float16*)ws; ws += (size_t)(3 * NHID * NHID) * 2;
  float* proj = (float*)ws;       ws += (size_t)MROWS * NOUT * 4;
  unsigned short* hbuf = (unsigned short*)ws;  ws += (size_t)BATCH * NHID * 2;
  unsigned short* rhbuf = (unsigned short*)ws; ws += (size_t)BATCH * NHID * 2;
  int* flags = (int*)ws;          ws += (size_t)NX * 256 * 4;   // 8 KB

  hipMemsetAsync(flags, 0, (size_t)NX * 256 * 4, stream);
  k_convert_x<<<2048, 256, 0, stream>>>(inputs, sememe, xh);
  k_convert_w<<<(NOUT * KDIM / 4) / 256, 256, 0, stream>>>(
      W_ioux, W_fx, b_ioux, b_fx, b_iouh, b_Uh, wbig, biasN);
  k_convert_wrec<<<(3 * NHID * NHID / 4) / 256, 256, 0, stream>>>(W_iouh, W_Uh, wrec);
  gemm_bt<<<(MROWS / 128) * (NOUT / 128), 256, 0, stream>>>(
      xh, wbig, biasN, proj, MROWS, NOUT, KDIM);
  recur7<<<NX * WPX, 256, 0, stream>>>(wrec, hx, proj, hbuf, rhbuf, flags, out);
}